// Round 6
// baseline (1840.790 us; speedup 1.0000x reference)
//
#include <hip/hip_runtime.h>
#include <cstdint>
#include <cstddef>

#define N_NODES 50000
#define N_EDGES 800000
#define D 128
#define DE 16
#define NBLK 196   // ceil(50000/256)

typedef float v2f __attribute__((ext_vector_type(2)));

// ---------------------------------------------------------------------------
// CSR build (dst-sorted, graph j=2, shared by both layers)
// ---------------------------------------------------------------------------
__global__ void csr_hist(const int* __restrict__ dst, int* __restrict__ count){
  int e = blockIdx.x*256 + threadIdx.x;
  if (e < N_EDGES) atomicAdd(&count[dst[e]], 1);
}

__global__ __launch_bounds__(256) void csr_blocksum(const int* __restrict__ count,
                                                    int* __restrict__ bsum){
  __shared__ int red[4];
  int i = blockIdx.x*256 + threadIdx.x;
  int v = (i < N_NODES) ? count[i] : 0;
  #pragma unroll
  for (int off=32; off; off>>=1) v += __shfl_down(v, off);
  if ((threadIdx.x & 63) == 0) red[threadIdx.x>>6] = v;
  __syncthreads();
  if (threadIdx.x == 0) bsum[blockIdx.x] = red[0]+red[1]+red[2]+red[3];
}

__global__ __launch_bounds__(256) void csr_scan_bsum(const int* __restrict__ bsum,
                                                     int* __restrict__ boff){
  __shared__ int s[256];
  int t = threadIdx.x;
  int v = (t < NBLK) ? bsum[t] : 0;
  s[t] = v; __syncthreads();
  for (int off=1; off<256; off<<=1){
    int u = (t >= off) ? s[t-off] : 0;
    __syncthreads(); s[t] += u; __syncthreads();
  }
  if (t < NBLK) boff[t] = s[t] - v;   // exclusive
}

__global__ __launch_bounds__(256) void csr_downsweep(const int* __restrict__ count,
    const int* __restrict__ boff, int* __restrict__ row_start, int* __restrict__ cursor){
  __shared__ int s[256];
  int t = threadIdx.x;
  int i = blockIdx.x*256 + t;
  int v = (i < N_NODES) ? count[i] : 0;
  s[t] = v; __syncthreads();
  for (int off=1; off<256; off<<=1){
    int u = (t >= off) ? s[t-off] : 0;
    __syncthreads(); s[t] += u; __syncthreads();
  }
  int excl = boff[blockIdx.x] + s[t] - v;
  if (i <= N_NODES) row_start[i] = excl;
  if (i <  N_NODES) cursor[i]   = excl;
}

__global__ void csr_scatter(const int* __restrict__ src, const int* __restrict__ dst,
                            int* __restrict__ cursor, int* __restrict__ perm,
                            int* __restrict__ src_perm){
  int e = blockIdx.x*256 + threadIdx.x;
  if (e >= N_EDGES) return;
  int d = dst[e];
  int pos = atomicAdd(&cursor[d], 1);
  perm[pos] = e;
  src_perm[pos] = src[e];
}

// ---------------------------------------------------------------------------
// LSTM stage 1: P0[t][r] = Wih[r] . W0[t] + (bih[r]+bhh[r])  — app 0 only.
// Apps 1,2 compute their input matvec in-block inside lstm_fused (their x is
// the previous app's h, produced on the previous wavefront diagonal).
// ---------------------------------------------------------------------------
__global__ __launch_bounds__(512) void lstm_pre(const float* __restrict__ Wih,
     const float* __restrict__ bih, const float* __restrict__ bhh,
     const float* __restrict__ xin, float* __restrict__ P){
  __shared__ float xs[128];
  int i = blockIdx.x >> 7, t = blockIdx.x & 127;
  const float* x = xin + (size_t)i*16384;
  if (threadIdx.x < 128) xs[threadIdx.x] = x[t*128 + threadIdx.x];
  __syncthreads();
  int r = threadIdx.x;
  const float4* wr = (const float4*)(Wih + (size_t)(i*512 + r)*128);
  const float4* x4 = (const float4*)xs;
  float acc = bih[i*512+r] + bhh[i*512+r];
  #pragma unroll
  for (int k=0;k<32;k++){
    float4 w = wr[k]; float4 xv = x4[k];
    acc += w.x*xv.x + w.y*xv.y + w.z*xv.z + w.w*xv.w;
  }
  P[(size_t)(i*128+t)*512 + r] = acc;
}

// ---------------------------------------------------------------------------
// LSTM stage 2: FUSED 3-application WAVEFRONT scan. One block per layer.
//
// Dependency: h_a(t) needs h_a(t-1) [recurrence, Whh] and h_{a-1}(t) [input,
// Wih] — cells (0,d),(1,d-1),(2,d-2) are independent -> process diagonally,
// 130 diagonals instead of 3x128 serial steps. The SAME LDS h-vector read
// serves both the recurrence of app a and the input matvec of app a+1.
//
// Layout: 512 thr = 8 waves = kc(4 K-chunks of 32) x rh(2 row halves).
// Lane: 4 rows (row0 = rh*256+l*4) x 32 K; weights whh+wih = 256 floats in
// the unified VGPR/AGPR file (launch_bounds(512,1) gives regalloc the full
// budget; prior rounds show the 128-float variant lives outside arch VGPRs
// with no penalty). Partials: partW[3][4][512], partP[2][4][512] — written
// as ds_write_b128 at lane-stride 16B (round-2/4 measured 0 bank conflicts);
// serial reads stride-4B conflict-free. hs single-buffered (read pre-B1,
// write post-B1, next read post-B2 — proven round-4 pattern).
// Per diagonal: up-to-5 matvecs (320 pk-fma/lane), B1, 3 independent serial
// gate-reductions (threads r<384: app=r>>7), B2.
// ---------------------------------------------------------------------------
__global__ __launch_bounds__(512, 1) void lstm_fused(
    const float* __restrict__ Whh, const float* __restrict__ Wih,
    const float* __restrict__ bih, const float* __restrict__ bhh,
    const float* __restrict__ P0, float* __restrict__ xout){
  __shared__ float hs[3][128];
  __shared__ float partW[3][4][512];
  __shared__ float partP[2][4][512];
  const int i  = blockIdx.x;           // layer
  const int r  = threadIdx.x;
  const int w  = r >> 6;
  const int l  = r & 63;
  const int kc = w >> 1;               // K-chunk id (0..3)
  const int rh = w & 1;                // row half
  const int row0 = rh*256 + l*4;       // 4 consecutive rows
  v2f whh[4][16], wih[4][16];
  {
    const float* bh = Whh + (size_t)i*65536 + (size_t)row0*128 + kc*32;
    const float* bw = Wih + (size_t)i*65536 + (size_t)row0*128 + kc*32;
    #pragma unroll
    for (int ri=0; ri<4; ri++){
      const v2f* ph = (const v2f*)(bh + ri*128);
      const v2f* pw = (const v2f*)(bw + ri*128);
      #pragma unroll
      for (int j=0;j<16;j++){ whh[ri][j] = ph[j]; wih[ri][j] = pw[j]; }
    }
  }
  const int sa = r >> 7;               // serial role: app id (active if <3)
  const int sj = r & 127;
  float b0=0.f,b1=0.f,b2=0.f,b3=0.f;   // bias for apps 1,2 (app0: in P0)
  if (sa==1 || sa==2){
    b0 = bih[i*512 +       sj] + bhh[i*512 +       sj];
    b1 = bih[i*512 + 128 + sj] + bhh[i*512 + 128 + sj];
    b2 = bih[i*512 + 256 + sj] + bhh[i*512 + 256 + sj];
    b3 = bih[i*512 + 384 + sj] + bhh[i*512 + 384 + sj];
  }
  float c = 0.f;
  float hreg = 0.f;
  if (r < 384) ((float*)hs)[r] = 0.f;  // zero-init all three h vectors
  __syncthreads();
  const float* Pi = P0 + (size_t)i*128*512;
  float* xo = xout + (size_t)i*128*128;
  for (int d=0; d<130; d++){
    // P0 row for app0's serial phase this diagonal (covered by FMA phase)
    float pc0=0.f,pc1=0.f,pc2=0.f,pc3=0.f;
    if (sa==0 && d<128){
      pc0 = Pi[d*512 +       sj];
      pc1 = Pi[d*512 + 128 + sj];
      pc2 = Pi[d*512 + 256 + sj];
      pc3 = Pi[d*512 + 384 + sj];
    }
    // FMA phase: per app, one h-read serves recurrence + next app's input
    #pragma unroll
    for (int a=0; a<3; a++){
      const int ta = d - a;                          // app a's step index
      const bool rec  = (ta >= 0) && (ta < 128);     // Whh @ h_a(ta-1)
      const bool feed = (a < 2) && (ta >= 1) && (ta <= 128); // Wih @ h_a(ta-1) for app a+1
      if (rec || feed){
        float4 hb[8];                                // h_a(ta-1) chunk (32 f)
        const float4* h4 = ((const float4*)hs[a]) + kc*8;
        #pragma unroll
        for (int j=0;j<8;j++) hb[j] = h4[j];
        const v2f* h2 = (const v2f*)hb;
        if (rec){
          v2f a0=(v2f)(0.f), a1=a0, a2=a0, a3=a0;
          #pragma unroll
          for (int j=0;j<16;j++){
            v2f hv = h2[j];
            a0 = __builtin_elementwise_fma(whh[0][j], hv, a0);
            a1 = __builtin_elementwise_fma(whh[1][j], hv, a1);
            a2 = __builtin_elementwise_fma(whh[2][j], hv, a2);
            a3 = __builtin_elementwise_fma(whh[3][j], hv, a3);
          }
          float4 pr;
          pr.x = a0.x + a0.y; pr.y = a1.x + a1.y;
          pr.z = a2.x + a2.y; pr.w = a3.x + a3.y;
          *(float4*)&partW[a][kc][row0] = pr;        // conflict-free b128
        }
        if (feed){
          v2f a0=(v2f)(0.f), a1=a0, a2=a0, a3=a0;
          #pragma unroll
          for (int j=0;j<16;j++){
            v2f hv = h2[j];
            a0 = __builtin_elementwise_fma(wih[0][j], hv, a0);
            a1 = __builtin_elementwise_fma(wih[1][j], hv, a1);
            a2 = __builtin_elementwise_fma(wih[2][j], hv, a2);
            a3 = __builtin_elementwise_fma(wih[3][j], hv, a3);
          }
          float4 pr;
          pr.x = a0.x + a0.y; pr.y = a1.x + a1.y;
          pr.z = a2.x + a2.y; pr.w = a3.x + a3.y;
          *(float4*)&partP[a][kc][row0] = pr;        // conflict-free b128
        }
      }
    }
    __syncthreads();                                 // B1
    const int ts = d - sa;
    if (sa < 3 && ts >= 0 && ts < 128){
      const int j0 = sj, j1 = 128+sj, j2 = 256+sj, j3 = 384+sj;
      float s0 = (partW[sa][0][j0]+partW[sa][1][j0])+(partW[sa][2][j0]+partW[sa][3][j0]);
      float s1 = (partW[sa][0][j1]+partW[sa][1][j1])+(partW[sa][2][j1]+partW[sa][3][j1]);
      float s2 = (partW[sa][0][j2]+partW[sa][1][j2])+(partW[sa][2][j2]+partW[sa][3][j2]);
      float s3 = (partW[sa][0][j3]+partW[sa][1][j3])+(partW[sa][2][j3]+partW[sa][3][j3]);
      if (sa == 0){
        s0 += pc0; s1 += pc1; s2 += pc2; s3 += pc3;
      } else {
        const float (*pp)[512] = partP[sa-1];
        s0 += ((pp[0][j0]+pp[1][j0])+(pp[2][j0]+pp[3][j0])) + b0;
        s1 += ((pp[0][j1]+pp[1][j1])+(pp[2][j1]+pp[3][j1])) + b1;
        s2 += ((pp[0][j2]+pp[1][j2])+(pp[2][j2]+pp[3][j2])) + b2;
        s3 += ((pp[0][j3]+pp[1][j3])+(pp[2][j3]+pp[3][j3])) + b3;
      }
      float gi = __builtin_amdgcn_rcpf(1.f + __expf(-s0));
      float gf = __builtin_amdgcn_rcpf(1.f + __expf(-s1));
      float xg = fminf(fmaxf(s2, -15.f), 15.f);
      float eg = __expf(2.f*xg);
      float gg = (eg - 1.f) * __builtin_amdgcn_rcpf(eg + 1.f);
      float go = __builtin_amdgcn_rcpf(1.f + __expf(-s3));
      c = gf*c + gi*gg;
      float xc = fminf(fmaxf(c, -15.f), 15.f);
      float e2 = __expf(2.f*xc);
      float th = (e2 - 1.f) * __builtin_amdgcn_rcpf(e2 + 1.f);
      hreg = go*th;
      hs[sa][sj] = hreg;                             // single-buffer: safe (B1/B2)
    }
    __syncthreads();                                 // B2
    if (sa == 2 && ts >= 0 && ts < 128) xo[ts*128 + sj] = hreg;  // app2 -> Wfin
  }
}

// ---------------------------------------------------------------------------
// GAT stage A: ft = f @ W (50000x128 @ 128x128, fp32) + s_src = f @ a_src
// Inner product uses packed-FP32 fma (v_pk_fma_f32) via float2 ext-vectors.
// ---------------------------------------------------------------------------
__global__ __launch_bounds__(256) void gat_transform(const float* __restrict__ f,
    const float* __restrict__ W, const float* __restrict__ aw,
    float* __restrict__ ft, float* __restrict__ s_src){
  __shared__ float Ws[64*128];
  __shared__ float fs[128*36];
  int n0 = blockIdx.x * 32;
  {
    int n = threadIdx.x >> 3, kq = threadIdx.x & 7;
    int gn = n0 + n;
    #pragma unroll
    for (int p=0;p<4;p++){
      int k = kq*16 + p*4;
      float4 v = make_float4(0.f,0.f,0.f,0.f);
      if (gn < N_NODES) v = *(const float4*)(f + (size_t)gn*128 + k);
      fs[(k+0)*36+n] = v.x; fs[(k+1)*36+n] = v.y;
      fs[(k+2)*36+n] = v.z; fs[(k+3)*36+n] = v.w;
    }
  }
  int jg = threadIdx.x & 31, ng = threadIdx.x >> 5;
  v2f A00=(v2f)(0.f), A01=A00, A10=A00, A11=A00;
  v2f A20=A00, A21=A00, A30=A00, A31=A00;
  for (int kk=0; kk<128; kk+=64){
    __syncthreads();
    {
      const float4* W4 = (const float4*)(W + (size_t)kk*128);
      float4* Ws4w = (float4*)Ws;
      for (int idx = threadIdx.x; idx < 2048; idx += 256) Ws4w[idx] = W4[idx];
    }
    __syncthreads();
    const float4* Ws4 = (const float4*)Ws;
    #pragma unroll 4
    for (int k2=0;k2<64;k2++){
      float4 wvv = Ws4[k2*32 + jg];
      v2f wl; wl.x = wvv.x; wl.y = wvv.y;
      v2f wh; wh.x = wvv.z; wh.y = wvv.w;
      float4 fv = *(const float4*)&fs[(kk+k2)*36 + (ng<<2)];
      v2f f0 = (v2f)(fv.x), f1 = (v2f)(fv.y), f2 = (v2f)(fv.z), f3 = (v2f)(fv.w);
      A00 = __builtin_elementwise_fma(wl, f0, A00);
      A01 = __builtin_elementwise_fma(wh, f0, A01);
      A10 = __builtin_elementwise_fma(wl, f1, A10);
      A11 = __builtin_elementwise_fma(wh, f1, A11);
      A20 = __builtin_elementwise_fma(wl, f2, A20);
      A21 = __builtin_elementwise_fma(wh, f2, A21);
      A30 = __builtin_elementwise_fma(wl, f3, A30);
      A31 = __builtin_elementwise_fma(wh, f3, A31);
    }
  }
  int nb = n0 + (ng<<2);
  float4 o0; o0.x=A00.x; o0.y=A00.y; o0.z=A01.x; o0.w=A01.y;
  float4 o1; o1.x=A10.x; o1.y=A10.y; o1.z=A11.x; o1.w=A11.y;
  float4 o2; o2.x=A20.x; o2.y=A20.y; o2.z=A21.x; o2.w=A21.y;
  float4 o3; o3.x=A30.x; o3.y=A30.y; o3.z=A31.x; o3.w=A31.y;
  if (nb+0 < N_NODES) *(float4*)(ft + (size_t)(nb+0)*128 + (jg<<2)) = o0;
  if (nb+1 < N_NODES) *(float4*)(ft + (size_t)(nb+1)*128 + (jg<<2)) = o1;
  if (nb+2 < N_NODES) *(float4*)(ft + (size_t)(nb+2)*128 + (jg<<2)) = o2;
  if (nb+3 < N_NODES) *(float4*)(ft + (size_t)(nb+3)*128 + (jg<<2)) = o3;
  if (threadIdx.x < 32){
    int gn = n0 + threadIdx.x;
    if (gn < N_NODES){
      float s = 0.f;
      for (int k=0;k<128;k++) s += fs[k*36 + threadIdx.x] * aw[k];
      s_src[gn] = s;
    }
  }
}

// ---------------------------------------------------------------------------
// GAT stage B: score[p] = s_src[src_perm[p]] + ef[perm[p]] . a_edge
// ---------------------------------------------------------------------------
__global__ __launch_bounds__(256) void gat_edge_score(const int* __restrict__ perm,
    const int* __restrict__ src_perm, const float* __restrict__ s_src,
    const float* __restrict__ ef, const float* __restrict__ aw,
    float* __restrict__ score){
  int p = blockIdx.x*256 + threadIdx.x;
  if (p >= N_EDGES) return;
  int e = perm[p];
  int s = src_perm[p];
  const float4* A = (const float4*)(aw + 128);
  float4 A0=A[0], A1=A[1], A2=A[2], A3=A[3];
  const float4* ev = (const float4*)(ef + (size_t)e*16);
  float4 v0=ev[0], v1=ev[1], v2=ev[2], v3=ev[3];
  float acc = s_src[s];
  acc += v0.x*A0.x + v0.y*A0.y + v0.z*A0.z + v0.w*A0.w;
  acc += v1.x*A1.x + v1.y*A1.y + v1.z*A1.z + v1.w*A1.w;
  acc += v2.x*A2.x + v2.y*A2.y + v2.z*A2.z + v2.w*A2.w;
  acc += v3.x*A3.x + v3.y*A3.y + v3.z*A3.z + v3.w*A3.w;
  score[p] = acc;
}

// ---------------------------------------------------------------------------
// GAT stage C: per-node softmax + alpha-weighted gather + leaky_relu
// Pass 2 stores exp(score-m) back into score (each p owned by exactly one
// lane of one node-wave -> no hazard), so the serial pass-3 loop is a
// multiply instead of an __expf on the dependency chain.
// ---------------------------------------------------------------------------
__global__ __launch_bounds__(256) void gat_aggregate(const int* __restrict__ row_start,
    const int* __restrict__ src_perm, float* __restrict__ score,
    const float* __restrict__ ft, float* __restrict__ out){
  int lane = threadIdx.x & 63;
  int wv = threadIdx.x >> 6;
  int n = blockIdx.x*4 + wv;
  if (n >= N_NODES) return;
  int s = row_start[n], e = row_start[n+1];
  float m = -1e30f;
  for (int p = s+lane; p < e; p += 64) m = fmaxf(m, score[p]);
  #pragma unroll
  for (int off=32; off; off>>=1) m = fmaxf(m, __shfl_xor(m, off));
  float den = 0.f;
  for (int p = s+lane; p < e; p += 64){
    float ex = __expf(score[p]-m);
    den += ex;
    score[p] = ex;
  }
  #pragma unroll
  for (int off=32; off; off>>=1) den += __shfl_xor(den, off);
  float inv = (den > 0.f) ? 1.f/den : 0.f;
  float a0 = 0.f, a1 = 0.f;
  for (int p = s; p < e; p++){
    float al = score[p]*inv;
    int sp = src_perm[p];
    float2 v = ((const float2*)(ft + (size_t)sp*128))[lane];
    a0 += al*v.x; a1 += al*v.y;
  }
  float2 o;
  o.x = (a0 > 0.f) ? a0 : 0.01f*a0;
  o.y = (a1 > 0.f) ? a1 : 0.01f*a1;
  ((float2*)(out + (size_t)n*128))[lane] = o;
}

// ---------------------------------------------------------------------------
extern "C" void kernel_launch(void* const* d_in, const int* in_sizes, int n_in,
                              void* d_out, int out_size, void* d_ws, size_t ws_size,
                              hipStream_t stream){
  (void)in_sizes; (void)n_in; (void)out_size; (void)ws_size;
  const int*   src     = (const int*)d_in[0] + (size_t)2*N_EDGES;       // j=2 slice
  const int*   dst     = (const int*)d_in[1] + (size_t)2*N_EDGES;
  const float* n_feats = (const float*)d_in[2] + (size_t)2*N_NODES*D;
  const float* e_feats = (const float*)d_in[3] + (size_t)2*N_EDGES*DE;
  const float* W0      = (const float*)d_in[4];
  const float* Wih     = (const float*)d_in[5];
  const float* Whh     = (const float*)d_in[6];
  const float* bih     = (const float*)d_in[7];
  const float* bhh     = (const float*)d_in[8];
  const float* a_w     = (const float*)d_in[9];
  float* out = (float*)d_out;

  char* wsp = (char*)d_ws;
  auto alloc = [&](size_t bytes)->char*{
    char* p = wsp; wsp += (bytes + 255) & ~(size_t)255; return p;
  };
  float* P         = (float*)alloc((size_t)2*128*512*4);
  float* Wfin      = (float*)alloc((size_t)2*128*128*4);
  int*   count     = (int*)  alloc((size_t)N_NODES*4);
  int*   bsum      = (int*)  alloc((size_t)NBLK*4);
  int*   boff      = (int*)  alloc((size_t)NBLK*4);
  int*   row_start = (int*)  alloc((size_t)(N_NODES+1)*4);
  int*   cursor    = (int*)  alloc((size_t)N_NODES*4);
  int*   perm      = (int*)  alloc((size_t)N_EDGES*4);
  int*   src_perm  = (int*)  alloc((size_t)N_EDGES*4);
  float* score     = (float*)alloc((size_t)N_EDGES*4);
  float* s_src     = (float*)alloc((size_t)N_NODES*4);
  float* ft        = (float*)alloc((size_t)N_NODES*D*4);
  float* f1        = (float*)alloc((size_t)N_NODES*D*4);

  // CSR build (once; same graph for both layers)
  hipMemsetAsync(count, 0, (size_t)N_NODES*4, stream);
  csr_hist     <<<(N_EDGES+255)/256, 256, 0, stream>>>(dst, count);
  csr_blocksum <<<NBLK, 256, 0, stream>>>(count, bsum);
  csr_scan_bsum<<<1,    256, 0, stream>>>(bsum, boff);
  csr_downsweep<<<NBLK, 256, 0, stream>>>(count, boff, row_start, cursor);
  csr_scatter  <<<(N_EDGES+255)/256, 256, 0, stream>>>(src, dst, cursor, perm, src_perm);

  // LSTM: app0 input matvec precomputed wide; then one fused wavefront kernel
  // runs all 3 applications x both layers (1 block per layer).
  lstm_pre  <<<256, 512, 0, stream>>>(Wih, bih, bhh, W0, P);
  lstm_fused<<<2,   512, 0, stream>>>(Whh, Wih, bih, bhh, P, Wfin);

  // Two GAT layers on graph j=2 (feats[0],feats[1] are dead w.r.t. output)
  const float* fin = n_feats;
  for (int l=0; l<2; l++){
    float* outl = (l==0) ? f1 : out;
    gat_transform <<<(N_NODES+31)/32, 256, 0, stream>>>(fin, Wfin + (size_t)l*16384,
                                                        a_w + (size_t)l*272, ft, s_src);
    gat_edge_score<<<(N_EDGES+255)/256, 256, 0, stream>>>(perm, src_perm, s_src,
                                                          e_feats, a_w + (size_t)l*272, score);
    gat_aggregate <<<N_NODES/4, 256, 0, stream>>>(row_start, src_perm, score, ft, outl);
    fin = f1;
  }
}

// Round 7
// 838.262 us; speedup vs baseline: 2.1960x; 2.1960x over previous
//
#include <hip/hip_runtime.h>
#include <cstdint>
#include <cstddef>

#define N_NODES 50000
#define N_EDGES 800000
#define D 128
#define DE 16
#define HB 1563     // ceil(800000/512) edge blocks at 512 thr
#define NB512 98    // ceil(50000/512) node blocks at 512 thr

typedef float v2f __attribute__((ext_vector_type(2)));

// ---------------------------------------------------------------------------
// Device bodies (shared by fused kernels). Each fused kernel role-switches on
// blockIdx.x; all barriers inside a body are executed by every thread of the
// blocks that take that path (no divergent-barrier hazard).
// ---------------------------------------------------------------------------

// LSTM stage 1: P[t][r] = Wih[r].x[t] + (bih[r]+bhh[r]); 256 blocks (i,t).
__device__ void lstm_pre_body(const float* __restrict__ Wih,
     const float* __restrict__ bih, const float* __restrict__ bhh,
     const float* __restrict__ xin, float* __restrict__ P, int bid){
  __shared__ float xs[128];
  int i = bid >> 7, t = bid & 127;
  const float* x = xin + (size_t)i*16384;
  if (threadIdx.x < 128) xs[threadIdx.x] = x[t*128 + threadIdx.x];
  __syncthreads();
  int r = threadIdx.x;
  const float4* wr = (const float4*)(Wih + (size_t)(i*512 + r)*128);
  const float4* x4 = (const float4*)xs;
  float acc = bih[i*512+r] + bhh[i*512+r];
  #pragma unroll
  for (int k=0;k<32;k++){
    float4 w = wr[k]; float4 xv = x4[k];
    acc += w.x*xv.x + w.y*xv.y + w.z*xv.z + w.w*xv.w;
  }
  P[(size_t)(i*128+t)*512 + r] = acc;
}

// LSTM stage 2: recurrent scan — ROUND-4 PROVEN BODY (98 µs): K-split,
// packed v_pk_fma_f32, conflict-free part[4][512] (measured 0 conflicts),
// __syncthreads barriers (round-5 showed lgkm-only barriers are SLOWER).
__device__ void lstm_scan_body(const float* __restrict__ Whh,
     const float* __restrict__ P, float* __restrict__ xout, int i){
  __shared__ float hs[128];
  __shared__ float part[4][512];
  const int r  = threadIdx.x;
  const int w  = r >> 6;
  const int l  = r & 63;
  const int kc = w >> 1;               // K-chunk id
  const int rh = w & 1;                // row half
  const int row0 = rh*256 + l*4;       // 4 consecutive rows
  v2f wv[4][16];
  {
    const float* base = Whh + (size_t)i*512*128 + (size_t)row0*128 + kc*32;
    #pragma unroll
    for (int ri=0; ri<4; ri++){
      const v2f* p2 = (const v2f*)(base + ri*128);
      #pragma unroll
      for (int j=0;j<16;j++) wv[ri][j] = p2[j];
    }
  }
  float c = 0.f;
  float hreg = 0.f;
  if (r < 128) hs[r] = 0.f;
  __syncthreads();
  const float* Pi = P + (size_t)i*128*512;
  float* xo = xout + (size_t)i*128*128;
  for (int t=0; t<128; t++){
    float p0=0.f, p1=0.f, p2=0.f, p3=0.f;
    if (r < 128){
      p0 = Pi[t*512 +   0 + r];
      p1 = Pi[t*512 + 128 + r];
      p2 = Pi[t*512 + 256 + r];
      p3 = Pi[t*512 + 384 + r];
    }
    float4 hbuf[8];
    {
      const float4* h4 = ((const float4*)hs) + kc*8;
      #pragma unroll
      for (int j=0;j<8;j++) hbuf[j] = h4[j];
    }
    const v2f* h2 = (const v2f*)hbuf;
    v2f a0 = (v2f)(0.f), a1 = (v2f)(0.f), a2 = (v2f)(0.f), a3 = (v2f)(0.f);
    #pragma unroll
    for (int j=0;j<16;j++){
      v2f hv = h2[j];
      a0 = __builtin_elementwise_fma(wv[0][j], hv, a0);
      a1 = __builtin_elementwise_fma(wv[1][j], hv, a1);
      a2 = __builtin_elementwise_fma(wv[2][j], hv, a2);
      a3 = __builtin_elementwise_fma(wv[3][j], hv, a3);
    }
    float4 pr;
    pr.x = a0.x + a0.y;
    pr.y = a1.x + a1.y;
    pr.z = a2.x + a2.y;
    pr.w = a3.x + a3.y;
    *(float4*)&part[kc][row0] = pr;      // conflict-free b128 (lane stride 16B)
    __syncthreads();                     // B1
    if (r < 128){
      int j = r;
      float s0 = ((part[0][      j] + part[1][      j]) + (part[2][      j] + part[3][      j])) + p0;
      float s1 = ((part[0][128 + j] + part[1][128 + j]) + (part[2][128 + j] + part[3][128 + j])) + p1;
      float s2 = ((part[0][256 + j] + part[1][256 + j]) + (part[2][256 + j] + part[3][256 + j])) + p2;
      float s3 = ((part[0][384 + j] + part[1][384 + j]) + (part[2][384 + j] + part[3][384 + j])) + p3;
      float gi = __builtin_amdgcn_rcpf(1.f + __expf(-s0));
      float gf = __builtin_amdgcn_rcpf(1.f + __expf(-s1));
      float xg = fminf(fmaxf(s2, -15.f), 15.f);
      float eg = __expf(2.f*xg);
      float gg = (eg - 1.f) * __builtin_amdgcn_rcpf(eg + 1.f);
      float go = __builtin_amdgcn_rcpf(1.f + __expf(-s3));
      c = gf*c + gi*gg;
      float xc = fminf(fmaxf(c, -15.f), 15.f);
      float e2 = __expf(2.f*xc);
      float th = (e2 - 1.f) * __builtin_amdgcn_rcpf(e2 + 1.f);
      hreg = go*th;
      hs[j] = hreg;
    }
    __syncthreads();                     // B2
    if (r < 128) xo[t*128 + r] = hreg;   // store drains under next FMA phase
  }
}

// CSR helpers, 512-thread granularity (unconditional barriers).
__device__ void csr_blocksum512(const int* __restrict__ count,
                                int* __restrict__ bsum, int b){
  __shared__ int red[8];
  int t = threadIdx.x;
  int i = b*512 + t;
  int v = (i < N_NODES) ? count[i] : 0;
  #pragma unroll
  for (int off=32; off; off>>=1) v += __shfl_down(v, off);
  if ((t & 63) == 0) red[t>>6] = v;
  __syncthreads();
  if (t == 0){
    int s = 0;
    #pragma unroll
    for (int k=0;k<8;k++) s += red[k];
    bsum[b] = s;
  }
}

__device__ void csr_scan_bsum512(const int* __restrict__ bsum,
                                 int* __restrict__ boff){
  __shared__ int s[512];
  int t = threadIdx.x;
  int v = (t < NB512) ? bsum[t] : 0;
  s[t] = v; __syncthreads();
  for (int off=1; off<512; off<<=1){
    int u = (t >= off) ? s[t-off] : 0;
    __syncthreads(); s[t] += u; __syncthreads();
  }
  if (t < NB512) boff[t] = s[t] - v;   // exclusive
}

__device__ void csr_downsweep512(const int* __restrict__ count,
    const int* __restrict__ boff, int* __restrict__ row_start,
    int* __restrict__ cursor, int b){
  __shared__ int s[512];
  int t = threadIdx.x;
  int i = b*512 + t;
  int v = (i < N_NODES) ? count[i] : 0;
  s[t] = v; __syncthreads();
  for (int off=1; off<512; off<<=1){
    int u = (t >= off) ? s[t-off] : 0;
    __syncthreads(); s[t] += u; __syncthreads();
  }
  int excl = boff[b] + s[t] - v;
  if (i <= N_NODES) row_start[i] = excl;
  if (i <  N_NODES) cursor[i]   = excl;
}

// ---------------------------------------------------------------------------
// Fused launches: role-switch on blockIdx. CSR phases + epart precompute ride
// on the 254 CUs idle during the 2-block LSTM scans (stream is serial, so
// standalone small kernels would otherwise sit on the critical path).
// ---------------------------------------------------------------------------
__global__ __launch_bounds__(512) void k_pre(const float* __restrict__ Wih,
     const float* __restrict__ bih, const float* __restrict__ bhh,
     const float* __restrict__ xin, float* __restrict__ P){
  lstm_pre_body(Wih, bih, bhh, xin, P, blockIdx.x);
}

// scan0 || csr_hist || epart[l][e] = ef[e] . a_edge_l (both layers).
__global__ __launch_bounds__(512, 2) void k_scan_hist_epart(
    const float* __restrict__ Whh, const float* __restrict__ P,
    float* __restrict__ xout, const int* __restrict__ dst,
    int* __restrict__ count, const float* __restrict__ ef,
    const float* __restrict__ aw, float* __restrict__ epart){
  int b = blockIdx.x;
  if (b < 2){ lstm_scan_body(Whh, P, xout, b); return; }
  b -= 2;
  if (b < HB){
    int e = b*512 + threadIdx.x;
    if (e < N_EDGES) atomicAdd(&count[dst[e]], 1);
    return;
  }
  b -= HB;
  int e = b*512 + threadIdx.x;
  if (e < N_EDGES){
    const float4* ev = (const float4*)(ef + (size_t)e*16);
    float4 v0=ev[0], v1=ev[1], v2=ev[2], v3=ev[3];
    #pragma unroll
    for (int l=0; l<2; l++){
      const float4* A = (const float4*)(aw + l*272 + 128);  // a_edge
      float4 A0=A[0], A1=A[1], A2=A[2], A3=A[3];
      float acc = v0.x*A0.x + v0.y*A0.y + v0.z*A0.z + v0.w*A0.w;
      acc      += v1.x*A1.x + v1.y*A1.y + v1.z*A1.z + v1.w*A1.w;
      acc      += v2.x*A2.x + v2.y*A2.y + v2.z*A2.z + v2.w*A2.w;
      acc      += v3.x*A3.x + v3.y*A3.y + v3.z*A3.z + v3.w*A3.w;
      epart[(size_t)l*N_EDGES + e] = acc;
    }
  }
}

__global__ __launch_bounds__(512) void k_pre_blocksum(const float* __restrict__ Wih,
     const float* __restrict__ bih, const float* __restrict__ bhh,
     const float* __restrict__ xin, float* __restrict__ P,
     const int* __restrict__ count, int* __restrict__ bsum){
  if (blockIdx.x < 256) lstm_pre_body(Wih, bih, bhh, xin, P, blockIdx.x);
  else                  csr_blocksum512(count, bsum, blockIdx.x - 256);
}

__global__ __launch_bounds__(512, 2) void k_scan_scanbsum(
    const float* __restrict__ Whh, const float* __restrict__ P,
    float* __restrict__ xout, const int* __restrict__ bsum,
    int* __restrict__ boff){
  if (blockIdx.x < 2) lstm_scan_body(Whh, P, xout, blockIdx.x);
  else                csr_scan_bsum512(bsum, boff);
}

__global__ __launch_bounds__(512) void k_pre_downsweep(const float* __restrict__ Wih,
     const float* __restrict__ bih, const float* __restrict__ bhh,
     const float* __restrict__ xin, float* __restrict__ P,
     const int* __restrict__ count, const int* __restrict__ boff,
     int* __restrict__ row_start, int* __restrict__ cursor){
  if (blockIdx.x < 256) lstm_pre_body(Wih, bih, bhh, xin, P, blockIdx.x);
  else                  csr_downsweep512(count, boff, row_start, cursor, blockIdx.x - 256);
}

__global__ __launch_bounds__(512, 2) void k_scan_scatter(
    const float* __restrict__ Whh, const float* __restrict__ P,
    float* __restrict__ xout, const int* __restrict__ src,
    const int* __restrict__ dst, int* __restrict__ cursor,
    int* __restrict__ perm, int* __restrict__ src_perm){
  int b = blockIdx.x;
  if (b < 2){ lstm_scan_body(Whh, P, xout, b); return; }
  int e = (b-2)*512 + threadIdx.x;
  if (e >= N_EDGES) return;
  int d = dst[e];
  int pos = atomicAdd(&cursor[d], 1);
  perm[pos] = e;
  src_perm[pos] = src[e];
}

// ---------------------------------------------------------------------------
// GAT stage A: ft = f @ W (50000x128 @ 128x128, fp32) + s_src = f @ a_src
// Inner product uses packed-FP32 fma (v_pk_fma_f32) via float2 ext-vectors.
// ---------------------------------------------------------------------------
__global__ __launch_bounds__(256) void gat_transform(const float* __restrict__ f,
    const float* __restrict__ W, const float* __restrict__ aw,
    float* __restrict__ ft, float* __restrict__ s_src){
  __shared__ float Ws[64*128];
  __shared__ float fs[128*36];
  int n0 = blockIdx.x * 32;
  {
    int n = threadIdx.x >> 3, kq = threadIdx.x & 7;
    int gn = n0 + n;
    #pragma unroll
    for (int p=0;p<4;p++){
      int k = kq*16 + p*4;
      float4 v = make_float4(0.f,0.f,0.f,0.f);
      if (gn < N_NODES) v = *(const float4*)(f + (size_t)gn*128 + k);
      fs[(k+0)*36+n] = v.x; fs[(k+1)*36+n] = v.y;
      fs[(k+2)*36+n] = v.z; fs[(k+3)*36+n] = v.w;
    }
  }
  int jg = threadIdx.x & 31, ng = threadIdx.x >> 5;
  v2f A00=(v2f)(0.f), A01=A00, A10=A00, A11=A00;
  v2f A20=A00, A21=A00, A30=A00, A31=A00;
  for (int kk=0; kk<128; kk+=64){
    __syncthreads();
    {
      const float4* W4 = (const float4*)(W + (size_t)kk*128);
      float4* Ws4w = (float4*)Ws;
      for (int idx = threadIdx.x; idx < 2048; idx += 256) Ws4w[idx] = W4[idx];
    }
    __syncthreads();
    const float4* Ws4 = (const float4*)Ws;
    #pragma unroll 4
    for (int k2=0;k2<64;k2++){
      float4 wvv = Ws4[k2*32 + jg];
      v2f wl; wl.x = wvv.x; wl.y = wvv.y;
      v2f wh; wh.x = wvv.z; wh.y = wvv.w;
      float4 fv = *(const float4*)&fs[(kk+k2)*36 + (ng<<2)];
      v2f f0 = (v2f)(fv.x), f1 = (v2f)(fv.y), f2 = (v2f)(fv.z), f3 = (v2f)(fv.w);
      A00 = __builtin_elementwise_fma(wl, f0, A00);
      A01 = __builtin_elementwise_fma(wh, f0, A01);
      A10 = __builtin_elementwise_fma(wl, f1, A10);
      A11 = __builtin_elementwise_fma(wh, f1, A11);
      A20 = __builtin_elementwise_fma(wl, f2, A20);
      A21 = __builtin_elementwise_fma(wh, f2, A21);
      A30 = __builtin_elementwise_fma(wl, f3, A30);
      A31 = __builtin_elementwise_fma(wh, f3, A31);
    }
  }
  int nb = n0 + (ng<<2);
  float4 o0; o0.x=A00.x; o0.y=A00.y; o0.z=A01.x; o0.w=A01.y;
  float4 o1; o1.x=A10.x; o1.y=A10.y; o1.z=A11.x; o1.w=A11.y;
  float4 o2; o2.x=A20.x; o2.y=A20.y; o2.z=A21.x; o2.w=A21.y;
  float4 o3; o3.x=A30.x; o3.y=A30.y; o3.z=A31.x; o3.w=A31.y;
  if (nb+0 < N_NODES) *(float4*)(ft + (size_t)(nb+0)*128 + (jg<<2)) = o0;
  if (nb+1 < N_NODES) *(float4*)(ft + (size_t)(nb+1)*128 + (jg<<2)) = o1;
  if (nb+2 < N_NODES) *(float4*)(ft + (size_t)(nb+2)*128 + (jg<<2)) = o2;
  if (nb+3 < N_NODES) *(float4*)(ft + (size_t)(nb+3)*128 + (jg<<2)) = o3;
  if (threadIdx.x < 32){
    int gn = n0 + threadIdx.x;
    if (gn < N_NODES){
      float s = 0.f;
      for (int k=0;k<128;k++) s += fs[k*36 + threadIdx.x] * aw[k];
      s_src[gn] = s;
    }
  }
}

// ---------------------------------------------------------------------------
// GAT stage B: score[p] = s_src[src_perm[p]] + epart_l[perm[p]]
// (ef . a_edge precomputed in edge order under the LSTM shadow; the gather
//  target is 3.2 MB -> L2-resident, vs the old 64B-random ef gather.)
// ---------------------------------------------------------------------------
__global__ __launch_bounds__(256) void gat_edge_score(const int* __restrict__ perm,
    const int* __restrict__ src_perm, const float* __restrict__ s_src,
    const float* __restrict__ epart_l, float* __restrict__ score){
  int p = blockIdx.x*256 + threadIdx.x;
  if (p >= N_EDGES) return;
  score[p] = s_src[src_perm[p]] + epart_l[perm[p]];
}

// ---------------------------------------------------------------------------
// GAT stage C: per-node softmax + alpha-weighted gather + leaky_relu
// ---------------------------------------------------------------------------
__global__ __launch_bounds__(256) void gat_aggregate(const int* __restrict__ row_start,
    const int* __restrict__ src_perm, float* __restrict__ score,
    const float* __restrict__ ft, float* __restrict__ out){
  int lane = threadIdx.x & 63;
  int wv = threadIdx.x >> 6;
  int n = blockIdx.x*4 + wv;
  if (n >= N_NODES) return;
  int s = row_start[n], e = row_start[n+1];
  float m = -1e30f;
  for (int p = s+lane; p < e; p += 64) m = fmaxf(m, score[p]);
  #pragma unroll
  for (int off=32; off; off>>=1) m = fmaxf(m, __shfl_xor(m, off));
  float den = 0.f;
  for (int p = s+lane; p < e; p += 64){
    float ex = __expf(score[p]-m);
    den += ex;
    score[p] = ex;
  }
  #pragma unroll
  for (int off=32; off; off>>=1) den += __shfl_xor(den, off);
  float inv = (den > 0.f) ? 1.f/den : 0.f;
  float a0 = 0.f, a1 = 0.f;
  for (int p = s; p < e; p++){
    float al = score[p]*inv;
    int sp = src_perm[p];
    float2 v = ((const float2*)(ft + (size_t)sp*128))[lane];
    a0 += al*v.x; a1 += al*v.y;
  }
  float2 o;
  o.x = (a0 > 0.f) ? a0 : 0.01f*a0;
  o.y = (a1 > 0.f) ? a1 : 0.01f*a1;
  ((float2*)(out + (size_t)n*128))[lane] = o;
}

// ---------------------------------------------------------------------------
extern "C" void kernel_launch(void* const* d_in, const int* in_sizes, int n_in,
                              void* d_out, int out_size, void* d_ws, size_t ws_size,
                              hipStream_t stream){
  (void)in_sizes; (void)n_in; (void)out_size; (void)ws_size;
  const int*   src     = (const int*)d_in[0] + (size_t)2*N_EDGES;       // j=2 slice
  const int*   dst     = (const int*)d_in[1] + (size_t)2*N_EDGES;
  const float* n_feats = (const float*)d_in[2] + (size_t)2*N_NODES*D;
  const float* e_feats = (const float*)d_in[3] + (size_t)2*N_EDGES*DE;
  const float* W0      = (const float*)d_in[4];
  const float* Wih     = (const float*)d_in[5];
  const float* Whh     = (const float*)d_in[6];
  const float* bih     = (const float*)d_in[7];
  const float* bhh     = (const float*)d_in[8];
  const float* a_w     = (const float*)d_in[9];
  float* out = (float*)d_out;

  char* wsp = (char*)d_ws;
  auto alloc = [&](size_t bytes)->char*{
    char* p = wsp; wsp += (bytes + 255) & ~(size_t)255; return p;
  };
  float* P         = (float*)alloc((size_t)2*128*512*4);
  float* xA        = (float*)alloc((size_t)2*128*128*4);
  float* xB        = (float*)alloc((size_t)2*128*128*4);
  int*   count     = (int*)  alloc((size_t)N_NODES*4);
  int*   bsum      = (int*)  alloc((size_t)NB512*4);
  int*   boff      = (int*)  alloc((size_t)NB512*4);
  int*   row_start = (int*)  alloc((size_t)(N_NODES+1)*4);
  int*   cursor    = (int*)  alloc((size_t)N_NODES*4);
  int*   perm      = (int*)  alloc((size_t)N_EDGES*4);
  int*   src_perm  = (int*)  alloc((size_t)N_EDGES*4);
  float* score     = (float*)alloc((size_t)N_EDGES*4);
  float* s_src     = (float*)alloc((size_t)N_NODES*4);
  float* epart     = (float*)alloc((size_t)2*N_EDGES*4);
  float* ft        = (float*)alloc((size_t)N_NODES*D*4);
  float* f1        = (float*)alloc((size_t)N_NODES*D*4);

  hipMemsetAsync(count, 0, (size_t)N_NODES*4, stream);

  // LSTM critical path with CSR/epart phases hidden under each launch:
  //   pre0 -> [scan0 || hist || epart] -> [pre1 || blocksum]
  //        -> [scan1 || scan_bsum] -> [pre2 || downsweep] -> [scan2 || scatter]
  k_pre            <<<256,        512, 0, stream>>>(Wih, bih, bhh, W0, P);
  k_scan_hist_epart<<<2 + 2*HB,   512, 0, stream>>>(Whh, P, xA, dst, count,
                                                    e_feats, a_w, epart);
  k_pre_blocksum   <<<256 + NB512,512, 0, stream>>>(Wih, bih, bhh, xA, P,
                                                    count, bsum);
  k_scan_scanbsum  <<<3,          512, 0, stream>>>(Whh, P, xB, bsum, boff);
  k_pre_downsweep  <<<256 + NB512,512, 0, stream>>>(Wih, bih, bhh, xB, P,
                                                    count, boff, row_start, cursor);
  k_scan_scatter   <<<2 + HB,     512, 0, stream>>>(Whh, P, xA, src, dst,
                                                    cursor, perm, src_perm);
  const float* Wfin = xA;   // scan0->xA, scan1->xB, scan2->xA

  // Two GAT layers on graph j=2 (feats[0],feats[1] dead w.r.t. output).
  // Note: reference adds s_dst[dst] to scores, but it is constant within each
  // dst softmax group -> cancels; omitted (inherited, verified passing).
  const float* fin = n_feats;
  for (int l=0; l<2; l++){
    float* outl = (l==0) ? f1 : out;
    gat_transform <<<(N_NODES+31)/32, 256, 0, stream>>>(fin, Wfin + (size_t)l*16384,
                                                        a_w + (size_t)l*272, ft, s_src);
    gat_edge_score<<<(N_EDGES+255)/256, 256, 0, stream>>>(perm, src_perm, s_src,
                                                          epart + (size_t)l*N_EDGES, score);
    gat_aggregate <<<N_NODES/4, 256, 0, stream>>>(row_start, src_perm, score, ft, outl);
    fin = f1;
  }
}

// Round 8
// 826.810 us; speedup vs baseline: 2.2264x; 1.0139x over previous
//
#include <hip/hip_runtime.h>
#include <cstdint>
#include <cstddef>

#define N_NODES 50000
#define N_EDGES 800000
#define D 128
#define DE 16
#define HB 1563     // ceil(800000/512) edge blocks at 512 thr
#define NB512 98    // ceil(50000/512) node blocks at 512 thr

typedef float v2f __attribute__((ext_vector_type(2)));

// ---------------------------------------------------------------------------
// Device bodies (shared by fused kernels). Each fused kernel role-switches on
// blockIdx.x; all barriers inside a body are executed by every thread of the
// blocks that take that path (no divergent-barrier hazard).
// ---------------------------------------------------------------------------

// LSTM stage 1: P[t][r] = Wih[r].x[t] + (bih[r]+bhh[r]); 256 blocks (i,t).
__device__ void lstm_pre_body(const float* __restrict__ Wih,
     const float* __restrict__ bih, const float* __restrict__ bhh,
     const float* __restrict__ xin, float* __restrict__ P, int bid){
  __shared__ float xs[128];
  int i = bid >> 7, t = bid & 127;
  const float* x = xin + (size_t)i*16384;
  if (threadIdx.x < 128) xs[threadIdx.x] = x[t*128 + threadIdx.x];
  __syncthreads();
  int r = threadIdx.x;
  const float4* wr = (const float4*)(Wih + (size_t)(i*512 + r)*128);
  const float4* x4 = (const float4*)xs;
  float acc = bih[i*512+r] + bhh[i*512+r];
  #pragma unroll
  for (int k=0;k<32;k++){
    float4 w = wr[k]; float4 xv = x4[k];
    acc += w.x*xv.x + w.y*xv.y + w.z*xv.z + w.w*xv.w;
  }
  P[(size_t)(i*128+t)*512 + r] = acc;
}

// LSTM stage 2: recurrent scan — ROUND-4 PROVEN BODY (98 µs): K-split,
// packed v_pk_fma_f32, conflict-free part[4][512] (measured 0 conflicts),
// __syncthreads barriers (round-5 showed lgkm-only barriers are SLOWER).
__device__ void lstm_scan_body(const float* __restrict__ Whh,
     const float* __restrict__ P, float* __restrict__ xout, int i){
  __shared__ float hs[128];
  __shared__ float part[4][512];
  const int r  = threadIdx.x;
  const int w  = r >> 6;
  const int l  = r & 63;
  const int kc = w >> 1;               // K-chunk id
  const int rh = w & 1;                // row half
  const int row0 = rh*256 + l*4;       // 4 consecutive rows
  v2f wv[4][16];
  {
    const float* base = Whh + (size_t)i*512*128 + (size_t)row0*128 + kc*32;
    #pragma unroll
    for (int ri=0; ri<4; ri++){
      const v2f* p2 = (const v2f*)(base + ri*128);
      #pragma unroll
      for (int j=0;j<16;j++) wv[ri][j] = p2[j];
    }
  }
  float c = 0.f;
  float hreg = 0.f;
  if (r < 128) hs[r] = 0.f;
  __syncthreads();
  const float* Pi = P + (size_t)i*128*512;
  float* xo = xout + (size_t)i*128*128;
  for (int t=0; t<128; t++){
    float p0=0.f, p1=0.f, p2=0.f, p3=0.f;
    if (r < 128){
      p0 = Pi[t*512 +   0 + r];
      p1 = Pi[t*512 + 128 + r];
      p2 = Pi[t*512 + 256 + r];
      p3 = Pi[t*512 + 384 + r];
    }
    float4 hbuf[8];
    {
      const float4* h4 = ((const float4*)hs) + kc*8;
      #pragma unroll
      for (int j=0;j<8;j++) hbuf[j] = h4[j];
    }
    const v2f* h2 = (const v2f*)hbuf;
    v2f a0 = (v2f)(0.f), a1 = (v2f)(0.f), a2 = (v2f)(0.f), a3 = (v2f)(0.f);
    #pragma unroll
    for (int j=0;j<16;j++){
      v2f hv = h2[j];
      a0 = __builtin_elementwise_fma(wv[0][j], hv, a0);
      a1 = __builtin_elementwise_fma(wv[1][j], hv, a1);
      a2 = __builtin_elementwise_fma(wv[2][j], hv, a2);
      a3 = __builtin_elementwise_fma(wv[3][j], hv, a3);
    }
    float4 pr;
    pr.x = a0.x + a0.y;
    pr.y = a1.x + a1.y;
    pr.z = a2.x + a2.y;
    pr.w = a3.x + a3.y;
    *(float4*)&part[kc][row0] = pr;      // conflict-free b128 (lane stride 16B)
    __syncthreads();                     // B1
    if (r < 128){
      int j = r;
      float s0 = ((part[0][      j] + part[1][      j]) + (part[2][      j] + part[3][      j])) + p0;
      float s1 = ((part[0][128 + j] + part[1][128 + j]) + (part[2][128 + j] + part[3][128 + j])) + p1;
      float s2 = ((part[0][256 + j] + part[1][256 + j]) + (part[2][256 + j] + part[3][256 + j])) + p2;
      float s3 = ((part[0][384 + j] + part[1][384 + j]) + (part[2][384 + j] + part[3][384 + j])) + p3;
      float gi = __builtin_amdgcn_rcpf(1.f + __expf(-s0));
      float gf = __builtin_amdgcn_rcpf(1.f + __expf(-s1));
      float xg = fminf(fmaxf(s2, -15.f), 15.f);
      float eg = __expf(2.f*xg);
      float gg = (eg - 1.f) * __builtin_amdgcn_rcpf(eg + 1.f);
      float go = __builtin_amdgcn_rcpf(1.f + __expf(-s3));
      c = gf*c + gi*gg;
      float xc = fminf(fmaxf(c, -15.f), 15.f);
      float e2 = __expf(2.f*xc);
      float th = (e2 - 1.f) * __builtin_amdgcn_rcpf(e2 + 1.f);
      hreg = go*th;
      hs[j] = hreg;
    }
    __syncthreads();                     // B2
    if (r < 128) xo[t*128 + r] = hreg;   // store drains under next FMA phase
  }
}

// CSR helpers, 512-thread granularity (unconditional barriers).
__device__ void csr_blocksum512(const int* __restrict__ count,
                                int* __restrict__ bsum, int b){
  __shared__ int red[8];
  int t = threadIdx.x;
  int i = b*512 + t;
  int v = (i < N_NODES) ? count[i] : 0;
  #pragma unroll
  for (int off=32; off; off>>=1) v += __shfl_down(v, off);
  if ((t & 63) == 0) red[t>>6] = v;
  __syncthreads();
  if (t == 0){
    int s = 0;
    #pragma unroll
    for (int k=0;k<8;k++) s += red[k];
    bsum[b] = s;
  }
}

__device__ void csr_scan_bsum512(const int* __restrict__ bsum,
                                 int* __restrict__ boff){
  __shared__ int s[512];
  int t = threadIdx.x;
  int v = (t < NB512) ? bsum[t] : 0;
  s[t] = v; __syncthreads();
  for (int off=1; off<512; off<<=1){
    int u = (t >= off) ? s[t-off] : 0;
    __syncthreads(); s[t] += u; __syncthreads();
  }
  if (t < NB512) boff[t] = s[t] - v;   // exclusive
}

__device__ void csr_downsweep512(const int* __restrict__ count,
    const int* __restrict__ boff, int* __restrict__ row_start,
    int* __restrict__ cursor, int b){
  __shared__ int s[512];
  int t = threadIdx.x;
  int i = b*512 + t;
  int v = (i < N_NODES) ? count[i] : 0;
  s[t] = v; __syncthreads();
  for (int off=1; off<512; off<<=1){
    int u = (t >= off) ? s[t-off] : 0;
    __syncthreads(); s[t] += u; __syncthreads();
  }
  int excl = boff[b] + s[t] - v;
  if (i <= N_NODES) row_start[i] = excl;
  if (i <  N_NODES) cursor[i]   = excl;
}

// ---------------------------------------------------------------------------
// Fused launches: role-switch on blockIdx. CSR phases + epart precompute ride
// on the 254 CUs idle during the 2-block LSTM scans.
// ---------------------------------------------------------------------------
__global__ __launch_bounds__(512) void k_pre(const float* __restrict__ Wih,
     const float* __restrict__ bih, const float* __restrict__ bhh,
     const float* __restrict__ xin, float* __restrict__ P){
  lstm_pre_body(Wih, bih, bhh, xin, P, blockIdx.x);
}

// scan0 || csr_hist || epart[e] = (ef[e].a_edge_0, ef[e].a_edge_1).
__global__ __launch_bounds__(512, 2) void k_scan_hist_epart(
    const float* __restrict__ Whh, const float* __restrict__ P,
    float* __restrict__ xout, const int* __restrict__ dst,
    int* __restrict__ count, const float* __restrict__ ef,
    const float* __restrict__ aw, float2* __restrict__ epart){
  int b = blockIdx.x;
  if (b < 2){ lstm_scan_body(Whh, P, xout, b); return; }
  b -= 2;
  if (b < HB){
    int e = b*512 + threadIdx.x;
    if (e < N_EDGES) atomicAdd(&count[dst[e]], 1);
    return;
  }
  b -= HB;
  int e = b*512 + threadIdx.x;
  if (e < N_EDGES){
    const float4* ev = (const float4*)(ef + (size_t)e*16);
    float4 v0=ev[0], v1=ev[1], v2=ev[2], v3=ev[3];
    float2 r;
    {
      const float4* A = (const float4*)(aw + 128);          // layer 0 a_edge
      float4 A0=A[0], A1=A[1], A2=A[2], A3=A[3];
      float acc = v0.x*A0.x + v0.y*A0.y + v0.z*A0.z + v0.w*A0.w;
      acc      += v1.x*A1.x + v1.y*A1.y + v1.z*A1.z + v1.w*A1.w;
      acc      += v2.x*A2.x + v2.y*A2.y + v2.z*A2.z + v2.w*A2.w;
      acc      += v3.x*A3.x + v3.y*A3.y + v3.z*A3.z + v3.w*A3.w;
      r.x = acc;
    }
    {
      const float4* A = (const float4*)(aw + 272 + 128);    // layer 1 a_edge
      float4 A0=A[0], A1=A[1], A2=A[2], A3=A[3];
      float acc = v0.x*A0.x + v0.y*A0.y + v0.z*A0.z + v0.w*A0.w;
      acc      += v1.x*A1.x + v1.y*A1.y + v1.z*A1.z + v1.w*A1.w;
      acc      += v2.x*A2.x + v2.y*A2.y + v2.z*A2.z + v2.w*A2.w;
      acc      += v3.x*A3.x + v3.y*A3.y + v3.z*A3.z + v3.w*A3.w;
      r.y = acc;
    }
    epart[e] = r;
  }
}

__global__ __launch_bounds__(512) void k_pre_blocksum(const float* __restrict__ Wih,
     const float* __restrict__ bih, const float* __restrict__ bhh,
     const float* __restrict__ xin, float* __restrict__ P,
     const int* __restrict__ count, int* __restrict__ bsum){
  if (blockIdx.x < 256) lstm_pre_body(Wih, bih, bhh, xin, P, blockIdx.x);
  else                  csr_blocksum512(count, bsum, blockIdx.x - 256);
}

__global__ __launch_bounds__(512, 2) void k_scan_scanbsum(
    const float* __restrict__ Whh, const float* __restrict__ P,
    float* __restrict__ xout, const int* __restrict__ bsum,
    int* __restrict__ boff){
  if (blockIdx.x < 2) lstm_scan_body(Whh, P, xout, blockIdx.x);
  else                csr_scan_bsum512(bsum, boff);
}

__global__ __launch_bounds__(512) void k_pre_downsweep(const float* __restrict__ Wih,
     const float* __restrict__ bih, const float* __restrict__ bhh,
     const float* __restrict__ xin, float* __restrict__ P,
     const int* __restrict__ count, const int* __restrict__ boff,
     int* __restrict__ row_start, int* __restrict__ cursor){
  if (blockIdx.x < 256) lstm_pre_body(Wih, bih, bhh, xin, P, blockIdx.x);
  else                  csr_downsweep512(count, boff, row_start, cursor, blockIdx.x - 256);
}

// scan2 || scatter. Payload PACKED into one int4 {src, e0_bits, e1_bits, 0}:
// one 16B store per edge -> 1 dirty 64B line per edge vs 2 with separate
// perm/src_perm arrays (round-7 measured WRITE_SIZE 81 MB ~= dispatch time).
__global__ __launch_bounds__(512, 2) void k_scan_scatter(
    const float* __restrict__ Whh, const float* __restrict__ P,
    float* __restrict__ xout, const int* __restrict__ src,
    const int* __restrict__ dst, const float2* __restrict__ epart,
    int* __restrict__ cursor, int4* __restrict__ edat){
  int b = blockIdx.x;
  if (b < 2){ lstm_scan_body(Whh, P, xout, b); return; }
  int e = (b-2)*512 + threadIdx.x;
  if (e >= N_EDGES) return;
  int d = dst[e];
  float2 ep = epart[e];
  int pos = atomicAdd(&cursor[d], 1);
  int4 v;
  v.x = src[e];
  v.y = __float_as_int(ep.x);
  v.z = __float_as_int(ep.y);
  v.w = 0;
  edat[pos] = v;
}

// ---------------------------------------------------------------------------
// GAT stage A: ft = f @ W (50000x128 @ 128x128, fp32) + s_src = f @ a_src
// Inner product uses packed-FP32 fma (v_pk_fma_f32) via float2 ext-vectors.
// ---------------------------------------------------------------------------
__global__ __launch_bounds__(256) void gat_transform(const float* __restrict__ f,
    const float* __restrict__ W, const float* __restrict__ aw,
    float* __restrict__ ft, float* __restrict__ s_src){
  __shared__ float Ws[64*128];
  __shared__ float fs[128*36];
  int n0 = blockIdx.x * 32;
  {
    int n = threadIdx.x >> 3, kq = threadIdx.x & 7;
    int gn = n0 + n;
    #pragma unroll
    for (int p=0;p<4;p++){
      int k = kq*16 + p*4;
      float4 v = make_float4(0.f,0.f,0.f,0.f);
      if (gn < N_NODES) v = *(const float4*)(f + (size_t)gn*128 + k);
      fs[(k+0)*36+n] = v.x; fs[(k+1)*36+n] = v.y;
      fs[(k+2)*36+n] = v.z; fs[(k+3)*36+n] = v.w;
    }
  }
  int jg = threadIdx.x & 31, ng = threadIdx.x >> 5;
  v2f A00=(v2f)(0.f), A01=A00, A10=A00, A11=A00;
  v2f A20=A00, A21=A00, A30=A00, A31=A00;
  for (int kk=0; kk<128; kk+=64){
    __syncthreads();
    {
      const float4* W4 = (const float4*)(W + (size_t)kk*128);
      float4* Ws4w = (float4*)Ws;
      for (int idx = threadIdx.x; idx < 2048; idx += 256) Ws4w[idx] = W4[idx];
    }
    __syncthreads();
    const float4* Ws4 = (const float4*)Ws;
    #pragma unroll 4
    for (int k2=0;k2<64;k2++){
      float4 wvv = Ws4[k2*32 + jg];
      v2f wl; wl.x = wvv.x; wl.y = wvv.y;
      v2f wh; wh.x = wvv.z; wh.y = wvv.w;
      float4 fv = *(const float4*)&fs[(kk+k2)*36 + (ng<<2)];
      v2f f0 = (v2f)(fv.x), f1 = (v2f)(fv.y), f2 = (v2f)(fv.z), f3 = (v2f)(fv.w);
      A00 = __builtin_elementwise_fma(wl, f0, A00);
      A01 = __builtin_elementwise_fma(wh, f0, A01);
      A10 = __builtin_elementwise_fma(wl, f1, A10);
      A11 = __builtin_elementwise_fma(wh, f1, A11);
      A20 = __builtin_elementwise_fma(wl, f2, A20);
      A21 = __builtin_elementwise_fma(wh, f2, A21);
      A30 = __builtin_elementwise_fma(wl, f3, A30);
      A31 = __builtin_elementwise_fma(wh, f3, A31);
    }
  }
  int nb = n0 + (ng<<2);
  float4 o0; o0.x=A00.x; o0.y=A00.y; o0.z=A01.x; o0.w=A01.y;
  float4 o1; o1.x=A10.x; o1.y=A10.y; o1.z=A11.x; o1.w=A11.y;
  float4 o2; o2.x=A20.x; o2.y=A20.y; o2.z=A21.x; o2.w=A21.y;
  float4 o3; o3.x=A30.x; o3.y=A30.y; o3.z=A31.x; o3.w=A31.y;
  if (nb+0 < N_NODES) *(float4*)(ft + (size_t)(nb+0)*128 + (jg<<2)) = o0;
  if (nb+1 < N_NODES) *(float4*)(ft + (size_t)(nb+1)*128 + (jg<<2)) = o1;
  if (nb+2 < N_NODES) *(float4*)(ft + (size_t)(nb+2)*128 + (jg<<2)) = o2;
  if (nb+3 < N_NODES) *(float4*)(ft + (size_t)(nb+3)*128 + (jg<<2)) = o3;
  if (threadIdx.x < 32){
    int gn = n0 + threadIdx.x;
    if (gn < N_NODES){
      float s = 0.f;
      for (int k=0;k<128;k++) s += fs[k*36 + threadIdx.x] * aw[k];
      s_src[gn] = s;
    }
  }
}

// ---------------------------------------------------------------------------
// GAT stage C (edge_score FUSED in): per-node online softmax + gather.
// Pass 1 (lane-strided): coalesced edat int4 + L2-resident s_src gather ->
//   score[p] stored; per-lane online (m, den) with rescale; cross-lane merge
//   via shfl_xor. Replaces the separate edge_score kernel + one strided
//   score pass + the exp-store pass.
// Pass 2 (serial over the segment): wave-uniform score/edat reads, exp+FMA.
// ---------------------------------------------------------------------------
__global__ __launch_bounds__(256) void gat_aggregate(const int* __restrict__ row_start,
    const int4* __restrict__ edat, const float* __restrict__ s_src,
    float* __restrict__ score, const float* __restrict__ ft,
    float* __restrict__ out, int layer){
  int lane = threadIdx.x & 63;
  int wv = threadIdx.x >> 6;
  int n = blockIdx.x*4 + wv;
  if (n >= N_NODES) return;
  int s = row_start[n], e = row_start[n+1];
  float m = -1e30f;
  float den = 0.f;
  for (int p = s+lane; p < e; p += 64){
    int4 v = edat[p];
    float el = __int_as_float(layer ? v.z : v.y);
    float sc = s_src[v.x] + el;
    score[p] = sc;
    float nm = fmaxf(m, sc);
    den = den*__expf(m - nm) + __expf(sc - nm);
    m = nm;
  }
  #pragma unroll
  for (int off=32; off; off>>=1){
    float m2 = __shfl_xor(m, off);
    float d2 = __shfl_xor(den, off);
    float nm = fmaxf(m, m2);
    den = den*__expf(m - nm) + d2*__expf(m2 - nm);
    m = nm;
  }
  float inv = (den > 0.f) ? 1.f/den : 0.f;
  float a0 = 0.f, a1 = 0.f;
  for (int p = s; p < e; p++){
    float al = __expf(score[p] - m)*inv;
    int sp = edat[p].x;
    float2 v = ((const float2*)(ft + (size_t)sp*128))[lane];
    a0 += al*v.x; a1 += al*v.y;
  }
  float2 o;
  o.x = (a0 > 0.f) ? a0 : 0.01f*a0;
  o.y = (a1 > 0.f) ? a1 : 0.01f*a1;
  ((float2*)(out + (size_t)n*128))[lane] = o;
}

// ---------------------------------------------------------------------------
extern "C" void kernel_launch(void* const* d_in, const int* in_sizes, int n_in,
                              void* d_out, int out_size, void* d_ws, size_t ws_size,
                              hipStream_t stream){
  (void)in_sizes; (void)n_in; (void)out_size; (void)ws_size;
  const int*   src     = (const int*)d_in[0] + (size_t)2*N_EDGES;       // j=2 slice
  const int*   dst     = (const int*)d_in[1] + (size_t)2*N_EDGES;
  const float* n_feats = (const float*)d_in[2] + (size_t)2*N_NODES*D;
  const float* e_feats = (const float*)d_in[3] + (size_t)2*N_EDGES*DE;
  const float* W0      = (const float*)d_in[4];
  const float* Wih     = (const float*)d_in[5];
  const float* Whh     = (const float*)d_in[6];
  const float* bih     = (const float*)d_in[7];
  const float* bhh     = (const float*)d_in[8];
  const float* a_w     = (const float*)d_in[9];
  float* out = (float*)d_out;

  char* wsp = (char*)d_ws;
  auto alloc = [&](size_t bytes)->char*{
    char* p = wsp; wsp += (bytes + 255) & ~(size_t)255; return p;
  };
  float*  P         = (float*) alloc((size_t)2*128*512*4);
  float*  xA        = (float*) alloc((size_t)2*128*128*4);
  float*  xB        = (float*) alloc((size_t)2*128*128*4);
  int*    count     = (int*)   alloc((size_t)N_NODES*4);
  int*    bsum      = (int*)   alloc((size_t)NB512*4);
  int*    boff      = (int*)   alloc((size_t)NB512*4);
  int*    row_start = (int*)   alloc((size_t)(N_NODES+1)*4);
  int*    cursor    = (int*)   alloc((size_t)N_NODES*4);
  int4*   edat      = (int4*)  alloc((size_t)N_EDGES*16);
  float*  score     = (float*) alloc((size_t)N_EDGES*4);
  float2* epart     = (float2*)alloc((size_t)N_EDGES*8);
  float*  s_src     = (float*) alloc((size_t)N_NODES*4);
  float*  ft        = (float*) alloc((size_t)N_NODES*D*4);
  float*  f1        = (float*) alloc((size_t)N_NODES*D*4);

  hipMemsetAsync(count, 0, (size_t)N_NODES*4, stream);

  // LSTM critical path with CSR/epart phases hidden under each launch:
  //   pre0 -> [scan0 || hist || epart] -> [pre1 || blocksum]
  //        -> [scan1 || scan_bsum] -> [pre2 || downsweep] -> [scan2 || scatter]
  k_pre            <<<256,        512, 0, stream>>>(Wih, bih, bhh, W0, P);
  k_scan_hist_epart<<<2 + 2*HB,   512, 0, stream>>>(Whh, P, xA, dst, count,
                                                    e_feats, a_w, epart);
  k_pre_blocksum   <<<256 + NB512,512, 0, stream>>>(Wih, bih, bhh, xA, P,
                                                    count, bsum);
  k_scan_scanbsum  <<<3,          512, 0, stream>>>(Whh, P, xB, bsum, boff);
  k_pre_downsweep  <<<256 + NB512,512, 0, stream>>>(Wih, bih, bhh, xB, P,
                                                    count, boff, row_start, cursor);
  k_scan_scatter   <<<2 + HB,     512, 0, stream>>>(Whh, P, xA, src, dst,
                                                    epart, cursor, edat);
  const float* Wfin = xA;   // scan0->xA, scan1->xB, scan2->xA

  // Two GAT layers on graph j=2 (feats[0],feats[1] dead w.r.t. output).
  // Note: reference adds s_dst[dst] to scores, but it is constant within each
  // dst softmax group -> cancels; omitted (inherited, verified passing).
  const float* fin = n_feats;
  for (int l=0; l<2; l++){
    float* outl = (l==0) ? f1 : out;
    gat_transform<<<(N_NODES+31)/32, 256, 0, stream>>>(fin, Wfin + (size_t)l*16384,
                                                       a_w + (size_t)l*272, ft, s_src);
    gat_aggregate<<<N_NODES/4, 256, 0, stream>>>(row_start, edat, s_src,
                                                 score, ft, outl, l);
    fin = f1;
  }
}